// Round 8
// baseline (1099.951 us; speedup 1.0000x reference)
//
#include <hip/hip_runtime.h>
#include <cstdint>

typedef long long ll;
typedef unsigned long long ull;

constexpr int N_ = 1024;           // atoms (fixed by problem)
constexpr int BLK = 256;
constexpr int NB  = 1024;          // classify / invalid-writer blocks (4/CU, 8/CU exact)
constexpr int RNDS = 54;           // rounds per classify block
constexpr int CHUNK = BLK * RNDS;  // 13824 pairs per block = 216 mask words
constexpr int WPW = 54;            // mask words per wave (invalid writer)
constexpr int Q4 = 27648;          // float4 zero-fill quota per classify block (T/NB)

// R8 = exact R6 (best, 698.5us) + ~440us end-spin on ONE thread of k_finish to
// surface its LIVE duration+counters in rocprof top-5 (displaces the 435us
// poison rows). The spin follows all real work of the LAST kernel -> does not
// perturb live contention; only delays next iteration's poison.
// Model so far: byte-floor 540us; early-overwrite of out elides poison L3
// drain (explains R2/R4/R5/R7 regressions of +46..+75); classify_fused ~85us
// is BW-consistent; finish ~160us vs ~80 BW-model is the unexplained gap.
__device__ __forceinline__ void spin_pad_end() {
  if (blockIdx.x == 0 && threadIdx.x == 0) {
    ll t0 = clock64();
    while (clock64() - t0 < 1050000ll) {}
  }
}

__device__ __forceinline__ ll rowstart(int i) {
  return (ll)i * (2 * N_ - 1 - i) / 2;
}

// invert triu(N,k=1) linear index -> (i,j)
__device__ __forceinline__ void decode_center(ll p, int& i, int& j) {
  double disc = (double)(2 * N_ - 1) * (double)(2 * N_ - 1) - 8.0 * (double)p;
  int ii = (int)(((double)(2 * N_ - 1) - sqrt(disc)) * 0.5);
  if (ii < 0) ii = 0;
  if (ii > N_ - 2) ii = N_ - 2;
  while (rowstart(ii) > p) --ii;
  while (rowstart(ii + 1) <= p) ++ii;
  i = ii;
  j = ii + 1 + (int)(p - rowstart(ii));
}

// ---------------- kernel 1: classify pairs -> bitmask + counts, FUSED zero-fill
// of out[2T,6T) as contiguous float4 streams overlapping the VALU classify work.
// Early overwrite of out ABSORBS the harness poison's dirty L3 (key to 698).
__global__ __launch_bounds__(BLK) void k_classify(
    const float* __restrict__ pos, const float* __restrict__ box,
    const int* __restrict__ shifts, int S, ll Pc, ll P, ll T4,
    float4* __restrict__ zp,
    ull* __restrict__ mask64, unsigned* __restrict__ blockCount,
    unsigned* __restrict__ cntA, unsigned* __restrict__ cntB,
    unsigned* __restrict__ cntC, unsigned* __restrict__ cntD)
{
  __shared__ float4 sp[N_];
  __shared__ float ssv[16][3];
  __shared__ unsigned wcnt[4];
  int tid = threadIdx.x;
  for (int a = tid; a < N_; a += BLK)
    sp[a] = make_float4(pos[3 * a + 0], pos[3 * a + 1], pos[3 * a + 2], 0.f);
  if (tid < S) {
    for (int k = 0; k < 3; ++k) {
      float acc = 0.f;
      for (int m = 0; m < 3; ++m)
        acc = __fadd_rn(acc, __fmul_rn((float)shifts[3 * tid + m], box[3 * m + k]));
      ssv[tid][k] = acc;
    }
  }
  __syncthreads();
  int lane = tid & 63, wave = tid >> 6;
  ll chunk = (ll)blockIdx.x * CHUNK;
  ll fillBase = (ll)blockIdx.x * Q4 + tid;
  const float4 z4 = make_float4(0.f, 0.f, 0.f, 0.f);
  unsigned wrun = 0;
  for (int r = 0; r < RNDS; ++r) {
    ll p0 = chunk + r * BLK + wave * 64;
    bool inr = (p0 < P);
    bool valid = false;
    if (inr) {
      ll p = p0 + lane;
      int i, j;
      float svx = 0.f, svy = 0.f, svz = 0.f;
      if (p < Pc) {
        decode_center(p, i, j);
      } else {
        ll q = p - Pc;
        int s = (int)(q >> 20);
        i = (int)((q >> 10) & (N_ - 1));
        j = (int)(q & (N_ - 1));
        svx = ssv[s][0]; svy = ssv[s][1]; svz = ssv[s][2];
      }
      float4 pi = sp[i], pj = sp[j];
      // strict IEEE order to match reference: (pi-pj)+sv, (x^2+y^2)+z^2, < 25.
      float dx = __fadd_rn(__fsub_rn(pi.x, pj.x), svx);
      float dy = __fadd_rn(__fsub_rn(pi.y, pj.y), svy);
      float dz = __fadd_rn(__fsub_rn(pi.z, pj.z), svz);
      float d2 = __fadd_rn(__fadd_rn(__fmul_rn(dx, dx), __fmul_rn(dy, dy)),
                           __fmul_rn(dz, dz));
      valid = (d2 < 25.0f);
      if (valid) {
        if (p < Pc) { atomicAdd(&cntA[i], 1u); atomicAdd(&cntC[j], 1u); }
        else        { atomicAdd(&cntB[i], 1u); atomicAdd(&cntD[j], 1u); }
      }
    }
    ull bal = __ballot(valid);
    if (lane == 0) {
      if (inr) mask64[p0 >> 6] = bal;
      wrun += (unsigned)__popcll(bal);
    }
    // fused zero-fill: 2 float4 per thread per round, contiguous per block
    ll f0 = fillBase + ((ll)r << 9);
    if (f0 < T4) zp[f0] = z4;
    ll f1 = f0 + BLK;
    if (f1 < T4) zp[f1] = z4;
  }
  if (lane == 0) wcnt[wave] = wrun;
  __syncthreads();
  if (tid == 0)
    blockCount[blockIdx.x] = wcnt[0] + wcnt[1] + wcnt[2] + wcnt[3];
}

// ---------------- kernel 1.5: bit-transpose of the shifted-region mask.
__global__ __launch_bounds__(BLK) void k_transpose(
    const ull* __restrict__ mskS, ull* __restrict__ maskT)
{
  __shared__ ull lds[64][17];   // +1 pad: avoid bank conflicts on col read
  int b = (int)blockIdx.x;
  int s = b >> 4, iw = b & 15;
  int tid = threadIdx.x, lane = tid & 63, wave = tid >> 6;
  ll base = ((ll)s << 14) + ((ll)iw << 10);
#pragma unroll
  for (int k = 0; k < 4; ++k) {
    int t = tid + (k << 8);     // t = (di<<4)|jw
    lds[t >> 4][t & 15] = mskS[base + t];
  }
  __syncthreads();
#pragma unroll
  for (int q = 0; q < 4; ++q) {
    int jw = (wave << 2) + q;
    ull myword = lds[lane][jw];           // word for i = iw*64+lane, bits over j
    ull keep = 0ull;
    for (int b2 = 0; b2 < 64; ++b2) {
      ull bal = __ballot((myword >> b2) & 1ull);
      if (b2 == lane) keep = bal;
    }
    maskT[((ll)s << 14) + ((ll)((jw << 6) + lane) << 4) + iw] = keep;
  }
}

// ---------------- kernel 2: fused finisher (R6) + end-spin diagnostic.
__global__ __launch_bounds__(BLK) void k_finish(
    const ull* __restrict__ mask64, const ull* __restrict__ maskT,
    const float* __restrict__ box,
    const int* __restrict__ shifts, int S, ll Pc, ll P, ll T,
    const unsigned* __restrict__ cntA, const unsigned* __restrict__ cntB,
    const unsigned* __restrict__ cntC, const unsigned* __restrict__ cntD,
    const unsigned* __restrict__ blockCount,
    float* __restrict__ out)
{
  __shared__ unsigned part[BLK];
  __shared__ unsigned res[8];
  __shared__ float ssv[16][3];
  __shared__ unsigned wq[4];
  int tid = threadIdx.x, lane = tid & 63, wave = tid >> 6;
  float* oi = out;
  float* oj = out + T;
  float* oo = out + 2 * T;
  float* ov = out + 5 * T;
  ull lt = (1ull << lane) - 1ull;

  if ((int)blockIdx.x < NB) {
    // ================= invalid writer =================
    int b = (int)blockIdx.x;
    unsigned mysum = 0;
    int e0 = 4 * tid;
#pragma unroll
    for (int e = 0; e < 4; ++e) mysum += blockCount[e0 + e];   // 256*4 = NB exact
    part[tid] = mysum;
    for (int off = 1; off < BLK; off <<= 1) {
      __syncthreads();
      unsigned x = (tid >= off) ? part[tid - off] : 0u;
      __syncthreads();
      part[tid] += x;
    }
    __syncthreads();
    if (tid == 0) {
      int q = b >> 2;
      unsigned excl = (q > 0) ? part[q - 1] : 0u;
      for (int m = 4 * q; m < b; ++m) excl += blockCount[m];
      res[0] = excl;            // valid count before this block
      res[1] = part[BLK - 1];   // Vp = total valid pair count
    }
    // per-wave span: 54 mask words, one per lane (lane<54)
    ll Wtot = P >> 6;           // P is word-aligned
    ll w0 = (ll)b * 216 + (ll)wave * WPW;
    ll widx = w0 + lane;
    ull myword = 0ull;
    if (lane < WPW) myword = (widx < Wtot) ? mask64[widx] : ~0ull; // fakes: no writes
    unsigned ws = (unsigned)__popcll(myword);
    for (int d = 1; d < 64; d <<= 1) ws += __shfl_xor(ws, d);
    if (lane == 0) wq[wave] = ws;
    __syncthreads();
    unsigned gv = res[0];
    for (int w2 = 0; w2 < 4; ++w2) if (w2 < wave) gv += wq[w2];
    unsigned Vp = res[1], V = 2u * Vp;
    ll invDelta = P - (ll)Vp;
    unsigned vrun = gv;
    for (int k = 0; k < WPW; ++k) {
      ull w64 = __shfl((long long)myword, k);
      ll p = ((w0 + k) << 6) + lane;
      bool invalid = !((w64 >> lane) & 1ull) && (p < P);
      if (invalid) {
        unsigned vb = vrun + (unsigned)__popcll(w64 & lt);
        ll posF = (ll)V + (p - (ll)vb);
        ll posR = posF + invDelta;
        int i, j;
        if (p < Pc) {
          decode_center(p, i, j);
        } else {
          ll q = p - Pc;
          i = (int)((q >> 10) & (N_ - 1));
          j = (int)(q & (N_ - 1));
        }
        float fi = (float)i, fj = (float)j;
        oi[posF] = fi; oj[posF] = fj;
        oi[posR] = fj; oj[posR] = fi;
      }
      vrun += (unsigned)__popcll(w64);
    }
  } else {
    // ================= valid scatter for atom a =================
    int a = (int)blockIdx.x - NB;
    if (tid < S) {
      for (int k = 0; k < 3; ++k) {
        float acc = 0.f;
        for (int m = 0; m < 3; ++m)
          acc = __fadd_rn(acc, __fmul_rn((float)shifts[3 * tid + m], box[3 * m + k]));
        ssv[tid][k] = acc;
      }
    }
    unsigned mysum = 0;
    int m0 = 4 * tid;   // 256 threads x 4 atoms = all 1024 atoms
#pragma unroll
    for (int e = 0; e < 4; ++e) {
      int m = m0 + e;
      mysum += cntA[m] + cntB[m] + cntC[m] + cntD[m];
    }
    part[tid] = mysum;
    for (int off = 1; off < BLK; off <<= 1) {
      __syncthreads();
      unsigned x = (tid >= off) ? part[tid - off] : 0u;
      __syncthreads();
      part[tid] += x;
    }
    __syncthreads();
    if (tid == 0) {
      int q = a >> 2;
      unsigned excl = (q > 0) ? part[q - 1] : 0u;
      for (int m = 4 * q; m < a; ++m)
        excl += cntA[m] + cntB[m] + cntC[m] + cntD[m];
      unsigned sA = excl;
      unsigned sB = sA + cntA[a];
      unsigned sC = sB + cntB[a];
      unsigned sD = sC + cntC[a];
      res[0] = sA; res[1] = sB; res[2] = sC; res[3] = sD;
    }
    __syncthreads();
    if (wave == 0) {               // A: center forward, row (a, j>a), offset = 0 (fill)
      unsigned run = res[0];
      int len = N_ - 1 - a;
      if (len > 0) {
        ll rb = rowstart(a);
        ll wb = rb >> 6;
        int off = (int)(rb & 63);
        int nw = (int)(((ll)off + len - 1) >> 6) + 1;   // words spanned (<=17)
        ull myw = (lane < nw) ? mask64[wb + lane] : 0ull;
        int steps = (len + 63) >> 6;
        for (int k = 0; k < steps; ++k) {
          int idx = (k << 6) + lane;
          int t = off + idx;                 // bit position relative to wb
          ull wsel = (ull)__shfl((long long)myw, t >> 6);
          bool v = (idx < len) && ((wsel >> (t & 63)) & 1ull);
          ull bal = __ballot(v);
          if (v) {
            ll pos = (ll)(run + (unsigned)__popcll(bal & lt));
            oi[pos] = (float)a; oj[pos] = (float)(a + 1 + idx); ov[pos] = 1.f;
          }
          run += (unsigned)__popcll(bal);
        }
      }
    } else if (wave == 1) {        // B: shifted forward (s, a, j), offset = -sv[s]
      unsigned run = res[1];
      ll wbB = (Pc >> 6) + ((ll)a << 4);
      int nwB = S * 16;
      ull wB[4];
#pragma unroll
      for (int g = 0; g < 4; ++g) {
        int n = lane + (g << 6);
        wB[g] = (n < nwB) ? mask64[wbB + (((ll)(n >> 4)) << 14) + (n & 15)] : 0ull;
      }
      float ox = 0.f, oy = 0.f, oz = 0.f;
#pragma unroll
      for (int g = 0; g < 4; ++g) {
        int lim = nwB - (g << 6); if (lim > 64) lim = 64;
        for (int t = 0; t < lim; ++t) {
          int n = (g << 6) + t;
          if ((n & 15) == 0) {
            int s = n >> 4;
            ox = -ssv[s][0]; oy = -ssv[s][1]; oz = -ssv[s][2];
          }
          ull w64 = (ull)__shfl((long long)wB[g], t);   // == ballot (bit idx = lane)
          if ((w64 >> lane) & 1ull) {
            ll pos = (ll)(run + (unsigned)__popcll(w64 & lt));
            int j = ((n & 15) << 6) + lane;
            oi[pos] = (float)a; oj[pos] = (float)j; ov[pos] = 1.f;
            oo[3 * pos + 0] = ox; oo[3 * pos + 1] = oy; oo[3 * pos + 2] = oz;
          }
          run += (unsigned)__popcll(w64);
        }
      }
    } else if (wave == 2) {        // C: center reversed (i < a, a), offset = 0 (fill)
      unsigned run = res[2];
      int steps = (a + 63) >> 6;
      for (int kb = 0; kb < steps; kb += 8) {
        ull wC[8];
#pragma unroll
        for (int kk = 0; kk < 8; ++kk) {
          int i = ((kb + kk) << 6) + lane;
          wC[kk] = 0ull;
          if (kb + kk < steps && i < a) {
            ll b2 = rowstart(i) + (a - i - 1);
            wC[kk] = mask64[b2 >> 6];
          }
        }
#pragma unroll
        for (int kk = 0; kk < 8; ++kk) {
          int k = kb + kk;
          if (k >= steps) break;
          int i = (k << 6) + lane;
          bool v = false;
          if (i < a) {
            ll b2 = rowstart(i) + (a - i - 1);
            v = (wC[kk] >> (b2 & 63)) & 1ull;
          }
          ull bal = __ballot(v);
          if (v) {
            ll pos = (ll)(run + (unsigned)__popcll(bal & lt));
            oi[pos] = (float)a; oj[pos] = (float)i; ov[pos] = 1.f;
          }
          run += (unsigned)__popcll(bal);
        }
      }
    } else {                       // D: shifted reversed (s, i, a), offset = +sv[s]
      // reads TRANSPOSED mask coalesced (R6), mirrors wave B.
      unsigned run = res[3];
      ll wbD = (ll)a << 4;
      int nwD = S * 16;
      ull wD[4];
#pragma unroll
      for (int g = 0; g < 4; ++g) {
        int n = lane + (g << 6);
        wD[g] = (n < nwD) ? maskT[(((ll)(n >> 4)) << 14) + wbD + (n & 15)] : 0ull;
      }
      float ox = 0.f, oy = 0.f, oz = 0.f;
#pragma unroll
      for (int g = 0; g < 4; ++g) {
        int lim = nwD - (g << 6); if (lim > 64) lim = 64;
        for (int t = 0; t < lim; ++t) {
          int n = (g << 6) + t;
          if ((n & 15) == 0) {
            int s = n >> 4;
            ox = ssv[s][0]; oy = ssv[s][1]; oz = ssv[s][2];
          }
          ull w64 = (ull)__shfl((long long)wD[g], t);
          if ((w64 >> lane) & 1ull) {
            ll pos = (ll)(run + (unsigned)__popcll(w64 & lt));
            int i = ((n & 15) << 6) + lane;
            oi[pos] = (float)a; oj[pos] = (float)i; ov[pos] = 1.f;
            oo[3 * pos + 0] = ox; oo[3 * pos + 1] = oy; oo[3 * pos + 2] = oz;
          }
          run += (unsigned)__popcll(w64);
        }
      }
    }
  }
  spin_pad_end();   // R8 diagnostic: surfaces k_finish's LIVE dur in top-5
}

static inline unsigned char* alignup(unsigned char* p, size_t a) {
  return (unsigned char*)(((uintptr_t)p + a - 1) & ~(uintptr_t)(a - 1));
}

extern "C" void kernel_launch(void* const* d_in, const int* in_sizes, int n_in,
                              void* d_out, int out_size, void* d_ws, size_t ws_size,
                              hipStream_t stream)
{
  const float* pos = (const float*)d_in[0];
  const float* box = (const float*)d_in[1];
  const int* shifts = (const int*)d_in[2];
  int S = in_sizes[2] / 3;                       // 13
  ll Pc = (ll)N_ * (N_ - 1) / 2;                 // 523776 (divisible by 64)
  ll P = Pc + (ll)S * N_ * N_;                   // 14,155,264 (word-aligned)
  ll T = 2 * P;                                  // 28,310,528
  ll T4 = T;                                     // float4 count of region [2T,6T)
  float* out = (float*)d_out;

  unsigned char* w = (unsigned char*)d_ws;
  ull* mask64 = (ull*)w;
  w += ((P + 63) / 64) * sizeof(ull);
  w = alignup(w, 256);
  unsigned* blockCount = (unsigned*)w; w += (size_t)NB * 4;
  w = alignup(w, 256);
  unsigned* cnt = (unsigned*)w;        w += (size_t)4 * N_ * 4;  // A,B,C,D contiguous
  unsigned* cntA = cnt, *cntB = cnt + N_, *cntC = cnt + 2 * N_, *cntD = cnt + 3 * N_;
  w = alignup(w, 256);
  ull* maskT = (ull*)w;                w += ((size_t)S << 14) * sizeof(ull);  // 1.7 MB

  // zero only the tiny atomic counters (16 KB); out[2T,6T) zero-fill is fused
  // into k_classify (overlaps its VALU work + absorbs poison dirty lines).
  hipMemsetAsync(cnt, 0, (size_t)4 * N_ * sizeof(unsigned), stream);

  k_classify<<<NB, BLK, 0, stream>>>(pos, box, shifts, S, Pc, P, T4,
                                     (float4*)(out + 2 * T),
                                     mask64, blockCount, cntA, cntB, cntC, cntD);
  k_transpose<<<S * 16, BLK, 0, stream>>>(mask64 + (Pc >> 6), maskT);
  k_finish<<<NB + N_, BLK, 0, stream>>>(mask64, maskT, box, shifts, S, Pc, P, T,
                                        cntA, cntB, cntC, cntD, blockCount, out);
}

// Round 9
// 684.981 us; speedup vs baseline: 1.6058x; 1.6058x over previous
//
#include <hip/hip_runtime.h>
#include <cstdint>

typedef long long ll;
typedef unsigned long long ull;

constexpr int N_ = 1024;           // atoms (fixed by problem)
constexpr int BLK = 256;
constexpr int NCLS = 2048;         // classify blocks (8/CU; R9: was 1024=4/CU)
constexpr int NINV = 1024;         // invalid-writer blocks (unchanged)
constexpr int RNDS = 27;           // rounds per classify block (halved with NCLS*2)
constexpr int CHUNK = BLK * RNDS;  // 6912 pairs per block = 108 mask words
constexpr int WPW = 54;            // mask words per wave (invalid writer)
constexpr int Q4 = 13824;          // float4 zero-fill quota per classify block (T/NCLS)

// R9: (1) k_transpose dispatch ELIMINATED -- maskT built in classify via one
// atomicOr per valid shifted pair (~10-20k total, trivial); maskT zeroing
// merged into the cnt memset (contiguous layout). (2) classify at 8/CU for
// better VALU/store overlap. Finish untouched (R8 measured live = 74us).
// Ledger @R6 698.5: 435 poison + ~150 classify + ~5 transpose + ~74 finish
// + ~35 gaps. Byte floor ~540. R4: NT stores regress. R5: fill must precede
// scatter in a separate dispatch. R7: late overwrite of out loses poison-drain
// absorption (+75us).

__device__ __forceinline__ ll rowstart(int i) {
  return (ll)i * (2 * N_ - 1 - i) / 2;
}

// invert triu(N,k=1) linear index -> (i,j)
__device__ __forceinline__ void decode_center(ll p, int& i, int& j) {
  double disc = (double)(2 * N_ - 1) * (double)(2 * N_ - 1) - 8.0 * (double)p;
  int ii = (int)(((double)(2 * N_ - 1) - sqrt(disc)) * 0.5);
  if (ii < 0) ii = 0;
  if (ii > N_ - 2) ii = N_ - 2;
  while (rowstart(ii) > p) --ii;
  while (rowstart(ii + 1) <= p) ++ii;
  i = ii;
  j = ii + 1 + (int)(p - rowstart(ii));
}

// ---------------- kernel 1: classify pairs -> bitmask + counts + maskT (via
// atomicOr), FUSED zero-fill of out[2T,6T). Early overwrite of out absorbs the
// harness poison's dirty L3 (key to the 698 baseline).
__global__ __launch_bounds__(BLK) void k_classify(
    const float* __restrict__ pos, const float* __restrict__ box,
    const int* __restrict__ shifts, int S, ll Pc, ll P, ll T4,
    float4* __restrict__ zp,
    ull* __restrict__ mask64, ull* __restrict__ maskT,
    unsigned* __restrict__ blockCount,
    unsigned* __restrict__ cntA, unsigned* __restrict__ cntB,
    unsigned* __restrict__ cntC, unsigned* __restrict__ cntD)
{
  __shared__ float4 sp[N_];
  __shared__ float ssv[16][3];
  __shared__ unsigned wcnt[4];
  int tid = threadIdx.x;
  for (int a = tid; a < N_; a += BLK)
    sp[a] = make_float4(pos[3 * a + 0], pos[3 * a + 1], pos[3 * a + 2], 0.f);
  if (tid < S) {
    for (int k = 0; k < 3; ++k) {
      float acc = 0.f;
      for (int m = 0; m < 3; ++m)
        acc = __fadd_rn(acc, __fmul_rn((float)shifts[3 * tid + m], box[3 * m + k]));
      ssv[tid][k] = acc;
    }
  }
  __syncthreads();
  int lane = tid & 63, wave = tid >> 6;
  ll chunk = (ll)blockIdx.x * CHUNK;
  ll fillBase = (ll)blockIdx.x * Q4 + tid;
  const float4 z4 = make_float4(0.f, 0.f, 0.f, 0.f);
  unsigned wrun = 0;
  for (int r = 0; r < RNDS; ++r) {
    ll p0 = chunk + r * BLK + wave * 64;
    bool inr = (p0 < P);
    bool valid = false;
    if (inr) {
      ll p = p0 + lane;
      int i, j;
      float svx = 0.f, svy = 0.f, svz = 0.f;
      bool center = (p < Pc);
      int s = 0;
      if (center) {
        decode_center(p, i, j);
      } else {
        ll q = p - Pc;
        s = (int)(q >> 20);
        i = (int)((q >> 10) & (N_ - 1));
        j = (int)(q & (N_ - 1));
        svx = ssv[s][0]; svy = ssv[s][1]; svz = ssv[s][2];
      }
      float4 pi = sp[i], pj = sp[j];
      // strict IEEE order to match reference: (pi-pj)+sv, (x^2+y^2)+z^2, < 25.
      float dx = __fadd_rn(__fsub_rn(pi.x, pj.x), svx);
      float dy = __fadd_rn(__fsub_rn(pi.y, pj.y), svy);
      float dz = __fadd_rn(__fsub_rn(pi.z, pj.z), svz);
      float d2 = __fadd_rn(__fadd_rn(__fmul_rn(dx, dx), __fmul_rn(dy, dy)),
                           __fmul_rn(dz, dz));
      valid = (d2 < 25.0f);
      if (valid) {
        if (center) { atomicAdd(&cntA[i], 1u); atomicAdd(&cntC[j], 1u); }
        else {
          atomicAdd(&cntB[i], 1u); atomicAdd(&cntD[j], 1u);
          // R9: build transposed shifted mask inline (replaces k_transpose).
          // word (s,j,iw) holds bit i&63 for i = iw*64+bit.
          atomicOr(&maskT[((ll)s << 14) + ((ll)j << 4) + (i >> 6)],
                   1ull << (i & 63));
        }
      }
    }
    ull bal = __ballot(valid);
    if (lane == 0) {
      if (inr) mask64[p0 >> 6] = bal;
      wrun += (unsigned)__popcll(bal);
    }
    // fused zero-fill: 2 float4 per thread per round, contiguous per block
    ll f0 = fillBase + ((ll)r << 9);
    if (f0 < T4) zp[f0] = z4;
    ll f1 = f0 + BLK;
    if (f1 < T4) zp[f1] = z4;
  }
  if (lane == 0) wcnt[wave] = wrun;
  __syncthreads();
  if (tid == 0)
    blockCount[blockIdx.x] = wcnt[0] + wcnt[1] + wcnt[2] + wcnt[3];
}

// ---------------- kernel 2: fused finisher. blocks [0,NINV): invalid idx
// writer (216 words per block = classify blocks [2b,2b+2)); blocks
// [NINV, NINV+N_): valid scatter for atom a. 2048 blocks = 8/CU.
__global__ __launch_bounds__(BLK) void k_finish(
    const ull* __restrict__ mask64, const ull* __restrict__ maskT,
    const float* __restrict__ box,
    const int* __restrict__ shifts, int S, ll Pc, ll P, ll T,
    const unsigned* __restrict__ cntA, const unsigned* __restrict__ cntB,
    const unsigned* __restrict__ cntC, const unsigned* __restrict__ cntD,
    const unsigned* __restrict__ blockCount,
    float* __restrict__ out)
{
  __shared__ unsigned part[BLK];
  __shared__ unsigned res[8];
  __shared__ float ssv[16][3];
  __shared__ unsigned wq[4];
  int tid = threadIdx.x, lane = tid & 63, wave = tid >> 6;
  float* oi = out;
  float* oj = out + T;
  float* oo = out + 2 * T;
  float* ov = out + 5 * T;
  ull lt = (1ull << lane) - 1ull;

  if ((int)blockIdx.x < NINV) {
    // ================= invalid writer =================
    int b = (int)blockIdx.x;
    // prefix over NCLS=2048 blockCount entries: 8 per thread
    unsigned mysum = 0;
    int e0 = 8 * tid;
#pragma unroll
    for (int e = 0; e < 8; ++e) mysum += blockCount[e0 + e];
    part[tid] = mysum;
    for (int off = 1; off < BLK; off <<= 1) {
      __syncthreads();
      unsigned x = (tid >= off) ? part[tid - off] : 0u;
      __syncthreads();
      part[tid] += x;
    }
    __syncthreads();
    if (tid == 0) {
      // exclusive sum of classify-block counts below entry 2b
      int q = (2 * b) >> 3;
      unsigned excl = (q > 0) ? part[q - 1] : 0u;
      for (int m = 8 * q; m < 2 * b; ++m) excl += blockCount[m];
      res[0] = excl;            // valid count before this block's word span
      res[1] = part[BLK - 1];   // Vp = total valid pair count
    }
    // per-wave span: 54 mask words, one per lane (lane<54)
    ll Wtot = P >> 6;           // P is word-aligned
    ll w0 = (ll)b * 216 + (ll)wave * WPW;
    ll widx = w0 + lane;
    ull myword = 0ull;
    if (lane < WPW) myword = (widx < Wtot) ? mask64[widx] : ~0ull; // fakes: no writes
    unsigned ws = (unsigned)__popcll(myword);
    for (int d = 1; d < 64; d <<= 1) ws += __shfl_xor(ws, d);
    if (lane == 0) wq[wave] = ws;
    __syncthreads();
    unsigned gv = res[0];
    for (int w2 = 0; w2 < 4; ++w2) if (w2 < wave) gv += wq[w2];
    unsigned Vp = res[1], V = 2u * Vp;
    ll invDelta = P - (ll)Vp;
    unsigned vrun = gv;
    for (int k = 0; k < WPW; ++k) {
      ull w64 = __shfl((long long)myword, k);
      ll p = ((w0 + k) << 6) + lane;
      bool invalid = !((w64 >> lane) & 1ull) && (p < P);
      if (invalid) {
        unsigned vb = vrun + (unsigned)__popcll(w64 & lt);
        ll posF = (ll)V + (p - (ll)vb);
        ll posR = posF + invDelta;
        int i, j;
        if (p < Pc) {
          decode_center(p, i, j);
        } else {
          ll q = p - Pc;
          i = (int)((q >> 10) & (N_ - 1));
          j = (int)(q & (N_ - 1));
        }
        float fi = (float)i, fj = (float)j;
        oi[posF] = fi; oj[posF] = fj;
        oi[posR] = fj; oj[posR] = fi;
      }
      vrun += (unsigned)__popcll(w64);
    }
  } else {
    // ================= valid scatter for atom a =================
    int a = (int)blockIdx.x - NINV;
    if (tid < S) {
      for (int k = 0; k < 3; ++k) {
        float acc = 0.f;
        for (int m = 0; m < 3; ++m)
          acc = __fadd_rn(acc, __fmul_rn((float)shifts[3 * tid + m], box[3 * m + k]));
        ssv[tid][k] = acc;
      }
    }
    unsigned mysum = 0;
    int m0 = 4 * tid;   // 256 threads x 4 atoms = all 1024 atoms
#pragma unroll
    for (int e = 0; e < 4; ++e) {
      int m = m0 + e;
      mysum += cntA[m] + cntB[m] + cntC[m] + cntD[m];
    }
    part[tid] = mysum;
    for (int off = 1; off < BLK; off <<= 1) {
      __syncthreads();
      unsigned x = (tid >= off) ? part[tid - off] : 0u;
      __syncthreads();
      part[tid] += x;
    }
    __syncthreads();
    if (tid == 0) {
      int q = a >> 2;
      unsigned excl = (q > 0) ? part[q - 1] : 0u;
      for (int m = 4 * q; m < a; ++m)
        excl += cntA[m] + cntB[m] + cntC[m] + cntD[m];
      unsigned sA = excl;
      unsigned sB = sA + cntA[a];
      unsigned sC = sB + cntB[a];
      unsigned sD = sC + cntC[a];
      res[0] = sA; res[1] = sB; res[2] = sC; res[3] = sD;
    }
    __syncthreads();
    if (wave == 0) {               // A: center forward, row (a, j>a), offset = 0 (fill)
      unsigned run = res[0];
      int len = N_ - 1 - a;
      if (len > 0) {
        ll rb = rowstart(a);
        ll wb = rb >> 6;
        int off = (int)(rb & 63);
        int nw = (int)(((ll)off + len - 1) >> 6) + 1;   // words spanned (<=17)
        ull myw = (lane < nw) ? mask64[wb + lane] : 0ull;
        int steps = (len + 63) >> 6;
        for (int k = 0; k < steps; ++k) {
          int idx = (k << 6) + lane;
          int t = off + idx;                 // bit position relative to wb
          ull wsel = (ull)__shfl((long long)myw, t >> 6);
          bool v = (idx < len) && ((wsel >> (t & 63)) & 1ull);
          ull bal = __ballot(v);
          if (v) {
            ll pos = (ll)(run + (unsigned)__popcll(bal & lt));
            oi[pos] = (float)a; oj[pos] = (float)(a + 1 + idx); ov[pos] = 1.f;
          }
          run += (unsigned)__popcll(bal);
        }
      }
    } else if (wave == 1) {        // B: shifted forward (s, a, j), offset = -sv[s]
      unsigned run = res[1];
      ll wbB = (Pc >> 6) + ((ll)a << 4);
      int nwB = S * 16;
      ull wB[4];
#pragma unroll
      for (int g = 0; g < 4; ++g) {
        int n = lane + (g << 6);
        wB[g] = (n < nwB) ? mask64[wbB + (((ll)(n >> 4)) << 14) + (n & 15)] : 0ull;
      }
      float ox = 0.f, oy = 0.f, oz = 0.f;
#pragma unroll
      for (int g = 0; g < 4; ++g) {
        int lim = nwB - (g << 6); if (lim > 64) lim = 64;
        for (int t = 0; t < lim; ++t) {
          int n = (g << 6) + t;
          if ((n & 15) == 0) {
            int s = n >> 4;
            ox = -ssv[s][0]; oy = -ssv[s][1]; oz = -ssv[s][2];
          }
          ull w64 = (ull)__shfl((long long)wB[g], t);   // == ballot (bit idx = lane)
          if ((w64 >> lane) & 1ull) {
            ll pos = (ll)(run + (unsigned)__popcll(w64 & lt));
            int j = ((n & 15) << 6) + lane;
            oi[pos] = (float)a; oj[pos] = (float)j; ov[pos] = 1.f;
            oo[3 * pos + 0] = ox; oo[3 * pos + 1] = oy; oo[3 * pos + 2] = oz;
          }
          run += (unsigned)__popcll(w64);
        }
      }
    } else if (wave == 2) {        // C: center reversed (i < a, a), offset = 0 (fill)
      unsigned run = res[2];
      int steps = (a + 63) >> 6;
      for (int kb = 0; kb < steps; kb += 8) {
        ull wC[8];
#pragma unroll
        for (int kk = 0; kk < 8; ++kk) {
          int i = ((kb + kk) << 6) + lane;
          wC[kk] = 0ull;
          if (kb + kk < steps && i < a) {
            ll b2 = rowstart(i) + (a - i - 1);
            wC[kk] = mask64[b2 >> 6];
          }
        }
#pragma unroll
        for (int kk = 0; kk < 8; ++kk) {
          int k = kb + kk;
          if (k >= steps) break;
          int i = (k << 6) + lane;
          bool v = false;
          if (i < a) {
            ll b2 = rowstart(i) + (a - i - 1);
            v = (wC[kk] >> (b2 & 63)) & 1ull;
          }
          ull bal = __ballot(v);
          if (v) {
            ll pos = (ll)(run + (unsigned)__popcll(bal & lt));
            oi[pos] = (float)a; oj[pos] = (float)i; ov[pos] = 1.f;
          }
          run += (unsigned)__popcll(bal);
        }
      }
    } else {                       // D: shifted reversed (s, i, a), offset = +sv[s]
      // reads TRANSPOSED mask coalesced (built by classify atomicOr).
      unsigned run = res[3];
      ll wbD = (ll)a << 4;
      int nwD = S * 16;
      ull wD[4];
#pragma unroll
      for (int g = 0; g < 4; ++g) {
        int n = lane + (g << 6);
        wD[g] = (n < nwD) ? maskT[(((ll)(n >> 4)) << 14) + wbD + (n & 15)] : 0ull;
      }
      float ox = 0.f, oy = 0.f, oz = 0.f;
#pragma unroll
      for (int g = 0; g < 4; ++g) {
        int lim = nwD - (g << 6); if (lim > 64) lim = 64;
        for (int t = 0; t < lim; ++t) {
          int n = (g << 6) + t;
          if ((n & 15) == 0) {
            int s = n >> 4;
            ox = ssv[s][0]; oy = ssv[s][1]; oz = ssv[s][2];
          }
          ull w64 = (ull)__shfl((long long)wD[g], t);
          if ((w64 >> lane) & 1ull) {
            ll pos = (ll)(run + (unsigned)__popcll(w64 & lt));
            int i = ((n & 15) << 6) + lane;
            oi[pos] = (float)a; oj[pos] = (float)i; ov[pos] = 1.f;
            oo[3 * pos + 0] = ox; oo[3 * pos + 1] = oy; oo[3 * pos + 2] = oz;
          }
          run += (unsigned)__popcll(w64);
        }
      }
    }
  }
}

static inline unsigned char* alignup(unsigned char* p, size_t a) {
  return (unsigned char*)(((uintptr_t)p + a - 1) & ~(uintptr_t)(a - 1));
}

extern "C" void kernel_launch(void* const* d_in, const int* in_sizes, int n_in,
                              void* d_out, int out_size, void* d_ws, size_t ws_size,
                              hipStream_t stream)
{
  const float* pos = (const float*)d_in[0];
  const float* box = (const float*)d_in[1];
  const int* shifts = (const int*)d_in[2];
  int S = in_sizes[2] / 3;                       // 13
  ll Pc = (ll)N_ * (N_ - 1) / 2;                 // 523776 (divisible by 64)
  ll P = Pc + (ll)S * N_ * N_;                   // 14,155,264 (word-aligned)
  ll T = 2 * P;                                  // 28,310,528
  ll T4 = T;                                     // float4 count of region [2T,6T)
  float* out = (float*)d_out;

  unsigned char* w = (unsigned char*)d_ws;
  ull* mask64 = (ull*)w;
  w += ((P + 63) / 64) * sizeof(ull);
  w = alignup(w, 256);
  unsigned* blockCount = (unsigned*)w; w += (size_t)NCLS * 4;
  w = alignup(w, 256);
  unsigned* cnt = (unsigned*)w;        w += (size_t)4 * N_ * 4;  // A,B,C,D contiguous
  unsigned* cntA = cnt, *cntB = cnt + N_, *cntC = cnt + 2 * N_, *cntD = cnt + 3 * N_;
  ull* maskT = (ull*)w;                w += ((size_t)S << 14) * sizeof(ull);  // 1.7 MB
  // cnt (16 KB) and maskT (1.7 MB) are contiguous: ONE memset covers both.

  hipMemsetAsync(cnt, 0,
                 (size_t)4 * N_ * sizeof(unsigned) + (((size_t)S << 14) * sizeof(ull)),
                 stream);

  k_classify<<<NCLS, BLK, 0, stream>>>(pos, box, shifts, S, Pc, P, T4,
                                       (float4*)(out + 2 * T),
                                       mask64, maskT, blockCount,
                                       cntA, cntB, cntC, cntD);
  k_finish<<<NINV + N_, BLK, 0, stream>>>(mask64, maskT, box, shifts, S, Pc, P, T,
                                          cntA, cntB, cntC, cntD, blockCount, out);
}

// Round 10
// 683.202 us; speedup vs baseline: 1.6100x; 1.0026x over previous
//
#include <hip/hip_runtime.h>
#include <cstdint>

typedef long long ll;
typedef unsigned long long ull;

constexpr int N_ = 1024;           // atoms (fixed by problem)
constexpr int BLK = 256;
constexpr int NCLS = 2048;         // classify blocks (8/CU)
constexpr int NINV = 1024;         // invalid-writer blocks
constexpr int RNDS = 27;           // rounds per classify block
constexpr int CHUNK = BLK * RNDS;  // 6912 pairs per block = 108 mask words
constexpr int WPW = 54;            // mask words per wave (invalid writer)

// R10: bulk zero-fill of out[2T,6T) moved to hipMemsetAsync BEFORE classify
// (rocclr fill kernel: proven 6.2 TB/s issue; L3 absorbs + drains under the
// following pure-VALU classify). Earliest-possible poison absorption. R2's
// failed split had fill AFTER classify -- this is the reverse order.
// Ledger @R9 685: 435 poison + ~150 classify_fused + ~74 finish + gaps.
// Fill-issue measured <38us when dedicated (R3) -> fused interleave was
// costing ~40-70us of serialization. If >=690 -> revert to R9, plateau.

__device__ __forceinline__ ll rowstart(int i) {
  return (ll)i * (2 * N_ - 1 - i) / 2;
}

// invert triu(N,k=1) linear index -> (i,j)
__device__ __forceinline__ void decode_center(ll p, int& i, int& j) {
  double disc = (double)(2 * N_ - 1) * (double)(2 * N_ - 1) - 8.0 * (double)p;
  int ii = (int)(((double)(2 * N_ - 1) - sqrt(disc)) * 0.5);
  if (ii < 0) ii = 0;
  if (ii > N_ - 2) ii = N_ - 2;
  while (rowstart(ii) > p) --ii;
  while (rowstart(ii + 1) <= p) ++ii;
  i = ii;
  j = ii + 1 + (int)(p - rowstart(ii));
}

// ---------------- kernel 1: classify pairs -> bitmask + counts + maskT
// (inline atomicOr). PURE compute: ~2 MB writes; overlaps the memset's drain.
__global__ __launch_bounds__(BLK) void k_classify(
    const float* __restrict__ pos, const float* __restrict__ box,
    const int* __restrict__ shifts, int S, ll Pc, ll P,
    ull* __restrict__ mask64, ull* __restrict__ maskT,
    unsigned* __restrict__ blockCount,
    unsigned* __restrict__ cntA, unsigned* __restrict__ cntB,
    unsigned* __restrict__ cntC, unsigned* __restrict__ cntD)
{
  __shared__ float4 sp[N_];
  __shared__ float ssv[16][3];
  __shared__ unsigned wcnt[4];
  int tid = threadIdx.x;
  for (int a = tid; a < N_; a += BLK)
    sp[a] = make_float4(pos[3 * a + 0], pos[3 * a + 1], pos[3 * a + 2], 0.f);
  if (tid < S) {
    for (int k = 0; k < 3; ++k) {
      float acc = 0.f;
      for (int m = 0; m < 3; ++m)
        acc = __fadd_rn(acc, __fmul_rn((float)shifts[3 * tid + m], box[3 * m + k]));
      ssv[tid][k] = acc;
    }
  }
  __syncthreads();
  int lane = tid & 63, wave = tid >> 6;
  ll chunk = (ll)blockIdx.x * CHUNK;
  unsigned wrun = 0;
  for (int r = 0; r < RNDS; ++r) {
    ll p0 = chunk + r * BLK + wave * 64;
    bool inr = (p0 < P);
    bool valid = false;
    if (inr) {
      ll p = p0 + lane;
      int i, j;
      float svx = 0.f, svy = 0.f, svz = 0.f;
      bool center = (p < Pc);
      int s = 0;
      if (center) {
        decode_center(p, i, j);
      } else {
        ll q = p - Pc;
        s = (int)(q >> 20);
        i = (int)((q >> 10) & (N_ - 1));
        j = (int)(q & (N_ - 1));
        svx = ssv[s][0]; svy = ssv[s][1]; svz = ssv[s][2];
      }
      float4 pi = sp[i], pj = sp[j];
      // strict IEEE order to match reference: (pi-pj)+sv, (x^2+y^2)+z^2, < 25.
      float dx = __fadd_rn(__fsub_rn(pi.x, pj.x), svx);
      float dy = __fadd_rn(__fsub_rn(pi.y, pj.y), svy);
      float dz = __fadd_rn(__fsub_rn(pi.z, pj.z), svz);
      float d2 = __fadd_rn(__fadd_rn(__fmul_rn(dx, dx), __fmul_rn(dy, dy)),
                           __fmul_rn(dz, dz));
      valid = (d2 < 25.0f);
      if (valid) {
        if (center) { atomicAdd(&cntA[i], 1u); atomicAdd(&cntC[j], 1u); }
        else {
          atomicAdd(&cntB[i], 1u); atomicAdd(&cntD[j], 1u);
          // transposed shifted mask: word (s,j,iw), bit i&63.
          atomicOr(&maskT[((ll)s << 14) + ((ll)j << 4) + (i >> 6)],
                   1ull << (i & 63));
        }
      }
    }
    ull bal = __ballot(valid);
    if (lane == 0) {
      if (inr) mask64[p0 >> 6] = bal;
      wrun += (unsigned)__popcll(bal);
    }
  }
  if (lane == 0) wcnt[wave] = wrun;
  __syncthreads();
  if (tid == 0)
    blockCount[blockIdx.x] = wcnt[0] + wcnt[1] + wcnt[2] + wcnt[3];
}

// ---------------- kernel 2: fused finisher (unchanged from R9).
__global__ __launch_bounds__(BLK) void k_finish(
    const ull* __restrict__ mask64, const ull* __restrict__ maskT,
    const float* __restrict__ box,
    const int* __restrict__ shifts, int S, ll Pc, ll P, ll T,
    const unsigned* __restrict__ cntA, const unsigned* __restrict__ cntB,
    const unsigned* __restrict__ cntC, const unsigned* __restrict__ cntD,
    const unsigned* __restrict__ blockCount,
    float* __restrict__ out)
{
  __shared__ unsigned part[BLK];
  __shared__ unsigned res[8];
  __shared__ float ssv[16][3];
  __shared__ unsigned wq[4];
  int tid = threadIdx.x, lane = tid & 63, wave = tid >> 6;
  float* oi = out;
  float* oj = out + T;
  float* oo = out + 2 * T;
  float* ov = out + 5 * T;
  ull lt = (1ull << lane) - 1ull;

  if ((int)blockIdx.x < NINV) {
    // ================= invalid writer =================
    int b = (int)blockIdx.x;
    unsigned mysum = 0;
    int e0 = 8 * tid;
#pragma unroll
    for (int e = 0; e < 8; ++e) mysum += blockCount[e0 + e];   // 256*8 = NCLS
    part[tid] = mysum;
    for (int off = 1; off < BLK; off <<= 1) {
      __syncthreads();
      unsigned x = (tid >= off) ? part[tid - off] : 0u;
      __syncthreads();
      part[tid] += x;
    }
    __syncthreads();
    if (tid == 0) {
      int q = (2 * b) >> 3;
      unsigned excl = (q > 0) ? part[q - 1] : 0u;
      for (int m = 8 * q; m < 2 * b; ++m) excl += blockCount[m];
      res[0] = excl;            // valid count before this block's word span
      res[1] = part[BLK - 1];   // Vp = total valid pair count
    }
    // per-wave span: 54 mask words, one per lane (lane<54)
    ll Wtot = P >> 6;           // P is word-aligned
    ll w0 = (ll)b * 216 + (ll)wave * WPW;
    ll widx = w0 + lane;
    ull myword = 0ull;
    if (lane < WPW) myword = (widx < Wtot) ? mask64[widx] : ~0ull; // fakes: no writes
    unsigned ws = (unsigned)__popcll(myword);
    for (int d = 1; d < 64; d <<= 1) ws += __shfl_xor(ws, d);
    if (lane == 0) wq[wave] = ws;
    __syncthreads();
    unsigned gv = res[0];
    for (int w2 = 0; w2 < 4; ++w2) if (w2 < wave) gv += wq[w2];
    unsigned Vp = res[1], V = 2u * Vp;
    ll invDelta = P - (ll)Vp;
    unsigned vrun = gv;
    for (int k = 0; k < WPW; ++k) {
      ull w64 = __shfl((long long)myword, k);
      ll p = ((w0 + k) << 6) + lane;
      bool invalid = !((w64 >> lane) & 1ull) && (p < P);
      if (invalid) {
        unsigned vb = vrun + (unsigned)__popcll(w64 & lt);
        ll posF = (ll)V + (p - (ll)vb);
        ll posR = posF + invDelta;
        int i, j;
        if (p < Pc) {
          decode_center(p, i, j);
        } else {
          ll q = p - Pc;
          i = (int)((q >> 10) & (N_ - 1));
          j = (int)(q & (N_ - 1));
        }
        float fi = (float)i, fj = (float)j;
        oi[posF] = fi; oj[posF] = fj;
        oi[posR] = fj; oj[posR] = fi;
      }
      vrun += (unsigned)__popcll(w64);
    }
  } else {
    // ================= valid scatter for atom a =================
    int a = (int)blockIdx.x - NINV;
    if (tid < S) {
      for (int k = 0; k < 3; ++k) {
        float acc = 0.f;
        for (int m = 0; m < 3; ++m)
          acc = __fadd_rn(acc, __fmul_rn((float)shifts[3 * tid + m], box[3 * m + k]));
        ssv[tid][k] = acc;
      }
    }
    unsigned mysum = 0;
    int m0 = 4 * tid;   // 256 threads x 4 atoms = all 1024 atoms
#pragma unroll
    for (int e = 0; e < 4; ++e) {
      int m = m0 + e;
      mysum += cntA[m] + cntB[m] + cntC[m] + cntD[m];
    }
    part[tid] = mysum;
    for (int off = 1; off < BLK; off <<= 1) {
      __syncthreads();
      unsigned x = (tid >= off) ? part[tid - off] : 0u;
      __syncthreads();
      part[tid] += x;
    }
    __syncthreads();
    if (tid == 0) {
      int q = a >> 2;
      unsigned excl = (q > 0) ? part[q - 1] : 0u;
      for (int m = 4 * q; m < a; ++m)
        excl += cntA[m] + cntB[m] + cntC[m] + cntD[m];
      unsigned sA = excl;
      unsigned sB = sA + cntA[a];
      unsigned sC = sB + cntB[a];
      unsigned sD = sC + cntC[a];
      res[0] = sA; res[1] = sB; res[2] = sC; res[3] = sD;
    }
    __syncthreads();
    if (wave == 0) {               // A: center forward, row (a, j>a), offset = 0 (fill)
      unsigned run = res[0];
      int len = N_ - 1 - a;
      if (len > 0) {
        ll rb = rowstart(a);
        ll wb = rb >> 6;
        int off = (int)(rb & 63);
        int nw = (int)(((ll)off + len - 1) >> 6) + 1;   // words spanned (<=17)
        ull myw = (lane < nw) ? mask64[wb + lane] : 0ull;
        int steps = (len + 63) >> 6;
        for (int k = 0; k < steps; ++k) {
          int idx = (k << 6) + lane;
          int t = off + idx;                 // bit position relative to wb
          ull wsel = (ull)__shfl((long long)myw, t >> 6);
          bool v = (idx < len) && ((wsel >> (t & 63)) & 1ull);
          ull bal = __ballot(v);
          if (v) {
            ll pos = (ll)(run + (unsigned)__popcll(bal & lt));
            oi[pos] = (float)a; oj[pos] = (float)(a + 1 + idx); ov[pos] = 1.f;
          }
          run += (unsigned)__popcll(bal);
        }
      }
    } else if (wave == 1) {        // B: shifted forward (s, a, j), offset = -sv[s]
      unsigned run = res[1];
      ll wbB = (Pc >> 6) + ((ll)a << 4);
      int nwB = S * 16;
      ull wB[4];
#pragma unroll
      for (int g = 0; g < 4; ++g) {
        int n = lane + (g << 6);
        wB[g] = (n < nwB) ? mask64[wbB + (((ll)(n >> 4)) << 14) + (n & 15)] : 0ull;
      }
      float ox = 0.f, oy = 0.f, oz = 0.f;
#pragma unroll
      for (int g = 0; g < 4; ++g) {
        int lim = nwB - (g << 6); if (lim > 64) lim = 64;
        for (int t = 0; t < lim; ++t) {
          int n = (g << 6) + t;
          if ((n & 15) == 0) {
            int s = n >> 4;
            ox = -ssv[s][0]; oy = -ssv[s][1]; oz = -ssv[s][2];
          }
          ull w64 = (ull)__shfl((long long)wB[g], t);   // == ballot (bit idx = lane)
          if ((w64 >> lane) & 1ull) {
            ll pos = (ll)(run + (unsigned)__popcll(w64 & lt));
            int j = ((n & 15) << 6) + lane;
            oi[pos] = (float)a; oj[pos] = (float)j; ov[pos] = 1.f;
            oo[3 * pos + 0] = ox; oo[3 * pos + 1] = oy; oo[3 * pos + 2] = oz;
          }
          run += (unsigned)__popcll(w64);
        }
      }
    } else if (wave == 2) {        // C: center reversed (i < a, a), offset = 0 (fill)
      unsigned run = res[2];
      int steps = (a + 63) >> 6;
      for (int kb = 0; kb < steps; kb += 8) {
        ull wC[8];
#pragma unroll
        for (int kk = 0; kk < 8; ++kk) {
          int i = ((kb + kk) << 6) + lane;
          wC[kk] = 0ull;
          if (kb + kk < steps && i < a) {
            ll b2 = rowstart(i) + (a - i - 1);
            wC[kk] = mask64[b2 >> 6];
          }
        }
#pragma unroll
        for (int kk = 0; kk < 8; ++kk) {
          int k = kb + kk;
          if (k >= steps) break;
          int i = (k << 6) + lane;
          bool v = false;
          if (i < a) {
            ll b2 = rowstart(i) + (a - i - 1);
            v = (wC[kk] >> (b2 & 63)) & 1ull;
          }
          ull bal = __ballot(v);
          if (v) {
            ll pos = (ll)(run + (unsigned)__popcll(bal & lt));
            oi[pos] = (float)a; oj[pos] = (float)i; ov[pos] = 1.f;
          }
          run += (unsigned)__popcll(bal);
        }
      }
    } else {                       // D: shifted reversed (s, i, a), offset = +sv[s]
      unsigned run = res[3];
      ll wbD = (ll)a << 4;
      int nwD = S * 16;
      ull wD[4];
#pragma unroll
      for (int g = 0; g < 4; ++g) {
        int n = lane + (g << 6);
        wD[g] = (n < nwD) ? maskT[(((ll)(n >> 4)) << 14) + wbD + (n & 15)] : 0ull;
      }
      float ox = 0.f, oy = 0.f, oz = 0.f;
#pragma unroll
      for (int g = 0; g < 4; ++g) {
        int lim = nwD - (g << 6); if (lim > 64) lim = 64;
        for (int t = 0; t < lim; ++t) {
          int n = (g << 6) + t;
          if ((n & 15) == 0) {
            int s = n >> 4;
            ox = ssv[s][0]; oy = ssv[s][1]; oz = ssv[s][2];
          }
          ull w64 = (ull)__shfl((long long)wD[g], t);
          if ((w64 >> lane) & 1ull) {
            ll pos = (ll)(run + (unsigned)__popcll(w64 & lt));
            int i = ((n & 15) << 6) + lane;
            oi[pos] = (float)a; oj[pos] = (float)i; ov[pos] = 1.f;
            oo[3 * pos + 0] = ox; oo[3 * pos + 1] = oy; oo[3 * pos + 2] = oz;
          }
          run += (unsigned)__popcll(w64);
        }
      }
    }
  }
}

static inline unsigned char* alignup(unsigned char* p, size_t a) {
  return (unsigned char*)(((uintptr_t)p + a - 1) & ~(uintptr_t)(a - 1));
}

extern "C" void kernel_launch(void* const* d_in, const int* in_sizes, int n_in,
                              void* d_out, int out_size, void* d_ws, size_t ws_size,
                              hipStream_t stream)
{
  const float* pos = (const float*)d_in[0];
  const float* box = (const float*)d_in[1];
  const int* shifts = (const int*)d_in[2];
  int S = in_sizes[2] / 3;                       // 13
  ll Pc = (ll)N_ * (N_ - 1) / 2;                 // 523776 (divisible by 64)
  ll P = Pc + (ll)S * N_ * N_;                   // 14,155,264 (word-aligned)
  ll T = 2 * P;                                  // 28,310,528
  float* out = (float*)d_out;

  unsigned char* w = (unsigned char*)d_ws;
  ull* mask64 = (ull*)w;
  w += ((P + 63) / 64) * sizeof(ull);
  w = alignup(w, 256);
  unsigned* blockCount = (unsigned*)w; w += (size_t)NCLS * 4;
  w = alignup(w, 256);
  unsigned* cnt = (unsigned*)w;        w += (size_t)4 * N_ * 4;  // A,B,C,D contiguous
  unsigned* cntA = cnt, *cntB = cnt + N_, *cntC = cnt + 2 * N_, *cntD = cnt + 3 * N_;
  ull* maskT = (ull*)w;                w += ((size_t)S << 14) * sizeof(ull);  // 1.7 MB
  // cnt (16 KB) and maskT (1.7 MB) contiguous: one memset covers both.

  // R10 ORDER: (1) bulk zero of out[2T,6T) FIRST -- earliest poison-dirty-line
  // absorption, via the 6.2 TB/s rocclr fill; (2) tiny cnt+maskT zero;
  // (3) pure classify (overlaps the bulk fill's L3 drain); (4) finish.
  hipMemsetAsync(out + 2 * T, 0, (size_t)(4 * T) * sizeof(float), stream);
  hipMemsetAsync(cnt, 0,
                 (size_t)4 * N_ * sizeof(unsigned) + (((size_t)S << 14) * sizeof(ull)),
                 stream);

  k_classify<<<NCLS, BLK, 0, stream>>>(pos, box, shifts, S, Pc, P,
                                       mask64, maskT, blockCount,
                                       cntA, cntB, cntC, cntD);
  k_finish<<<NINV + N_, BLK, 0, stream>>>(mask64, maskT, box, shifts, S, Pc, P, T,
                                          cntA, cntB, cntC, cntD, blockCount, out);
}